// Round 3
// baseline (304.535 us; speedup 1.0000x reference)
//
#include <hip/hip_runtime.h>
#include <hip/hip_bf16.h>
#include <hip/hip_cooperative_groups.h>
#include <stdint.h>

namespace cg = cooperative_groups;

#define Bn 4
#define Cn 64
#define Fn 50000
#define Kn 16
#define NTOT (Bn*Fn)
#define EPS 1e-5f
#define NSUB 2048          // virtual sub-blocks for gather phase (512 per b)

typedef unsigned short u16;
typedef unsigned int u32;
typedef __attribute__((ext_vector_type(8))) short short8;
typedef __attribute__((ext_vector_type(4))) float f32x4;
typedef __attribute__((ext_vector_type(2))) float f32x2;
typedef __attribute__((ext_vector_type(4))) int i32x4;
typedef __attribute__((ext_vector_type(4))) unsigned int u32x4;

__device__ __forceinline__ u16 f2bf(float x) {
  __hip_bfloat16 h = __float2bfloat16(x);
  return *reinterpret_cast<u16*>(&h);
}
__device__ __forceinline__ u32 pack2(float a, float b) {
  return (u32)f2bf(a) | ((u32)f2bf(b) << 16);
}
__device__ __forceinline__ f32x2 up2(u32 uu) {     // bf16 pair -> f32 pair
  f32x2 r;
  r.x = __uint_as_float(uu << 16);
  r.y = __uint_as_float(uu & 0xffff0000u);
  return r;
}

// K1 (MFMA): Gt[b][face][64ch] bf16 (128 B rows) = W x fea[b].
// Also zeroes gsum (block 0,0) so no separate memset dispatch is needed.
__global__ __launch_bounds__(256) void k1_mfma(
    const float* __restrict__ fea, const float* __restrict__ W,
    u32* __restrict__ Gt, float* __restrict__ gsum) {
  const int b = blockIdx.y;
  const int f0 = blockIdx.x * 128;
  const int t = threadIdx.x;
  const int l = t & 63;
  const int quad = l >> 4;
  const int lane15 = l & 15;
  const int wv = t >> 6;
  __shared__ float a_s[64][129];   // 33 KB -> 4 blocks/CU

  if (blockIdx.x == 0 && b == 0 && t < 128) gsum[t] = 0.f;

  // A-frags: o = ot*16 + lane15, c = kk*32 + quad*8 + j
  short8 afr[4][2];
  #pragma unroll
  for (int ot = 0; ot < 4; ot++) {
    #pragma unroll
    for (int kk = 0; kk < 2; kk++) {
      const float* wr = W + (ot * 16 + lane15) * 64 + kk * 32 + quad * 8;
      float4 wa = *(const float4*)wr;
      float4 wb = *(const float4*)(wr + 4);
      union { short8 v; u32 u[4]; } fr;
      fr.u[0] = pack2(wa.x, wa.y); fr.u[1] = pack2(wa.z, wa.w);
      fr.u[2] = pack2(wb.x, wb.y); fr.u[3] = pack2(wb.z, wb.w);
      afr[ot][kk] = fr.v;
    }
  }

  // Stage: 8 independent float4 loads/thread, each half-wave reads a 512 B run
  {
    const float* fb = fea + (size_t)b * Cn * Fn;
    const int f4 = t & 31;          // float4 slot within 128-f tile
    const int cbase = t >> 5;       // 0..7
    const bool fvalid = (f0 + f4 * 4) < Fn;   // Fn%4==0 -> whole float4 valid
    #pragma unroll
    for (int jj = 0; jj < 8; jj++) {
      int c = cbase + jj * 8;
      float4 v = make_float4(0.f, 0.f, 0.f, 0.f);
      if (fvalid) v = *(const float4*)(fb + (size_t)c * Fn + f0 + f4 * 4);
      *(float4*)&a_s[c][f4 * 4] = v;
    }
  }
  __syncthreads();

  f32x4 acc[4][2];
  #pragma unroll
  for (int ot = 0; ot < 4; ot++)
    #pragma unroll
    for (int ft = 0; ft < 2; ft++) acc[ot][ft] = (f32x4){0.f, 0.f, 0.f, 0.f};

  #pragma unroll
  for (int ft = 0; ft < 2; ft++) {
    const int fl = wv * 32 + ft * 16 + lane15;
    float x[16];
    #pragma unroll
    for (int j = 0; j < 8; j++) x[j] = a_s[quad * 8 + j][fl];
    #pragma unroll
    for (int j = 0; j < 8; j++) x[8 + j] = a_s[32 + quad * 8 + j][fl];
    union { short8 s; u32 u[4]; } b0, b1;
    #pragma unroll
    for (int p = 0; p < 4; p++) {
      b0.u[p] = pack2(x[2 * p], x[2 * p + 1]);
      b1.u[p] = pack2(x[8 + 2 * p], x[8 + 2 * p + 1]);
    }
    #pragma unroll
    for (int ot = 0; ot < 4; ot++) {
      acc[ot][ft] = __builtin_amdgcn_mfma_f32_16x16x32_bf16(afr[ot][0], b0.s, acc[ot][ft], 0, 0, 0);
      acc[ot][ft] = __builtin_amdgcn_mfma_f32_16x16x32_bf16(afr[ot][1], b1.s, acc[ot][ft], 0, 0, 0);
    }
  }

  // Epilogue: transpose through LDS (reuse a_s as u32, row stride 36) then
  // write 128 faces x 128 B fully contiguous.
  __syncthreads();                 // all waves done reading a_s
  u32* ts = (u32*)&a_s[0][0];      // 128 * 36 * 4 B = 18.4 KB
  #pragma unroll
  for (int ot = 0; ot < 4; ot++) {
    #pragma unroll
    for (int ft = 0; ft < 2; ft++) {
      int fl = wv * 32 + ft * 16 + lane15;
      uint2 pv;
      pv.x = pack2(acc[ot][ft][0], acc[ot][ft][1]);
      pv.y = pack2(acc[ot][ft][2], acc[ot][ft][3]);
      *(uint2*)&ts[fl * 36 + ot * 8 + quad * 2] = pv;   // slot j covers ch (2j,2j+1)
    }
  }
  __syncthreads();
  #pragma unroll
  for (int j = 0; j < 4; j++) {
    int o = j * 1024 + t * 4;       // u32 offset in 128x32 tile
    int fl = o >> 5, sl = o & 31;
    if (f0 + fl < Fn) {
      u32x4 vv = *(const u32x4*)&ts[fl * 36 + sl];
      *(u32x4*)(Gt + ((size_t)b * Fn + f0 + fl) * 32 + sl) = vv;
    }
  }
}

// K2F (cooperative): gather+bias+stats -> grid.sync -> BN-normalize+relu.
// Phase 1: virtual sub vs in [0,2048): b=(vs&7)>>1, sub within b; 32-face
// tiles, 8-thread groups fetch one 128 B Gt row per neighbor. Stats in
// packed-f32 registers; one LDS reduce + atomic round per block.
// Phase 3: same block re-reads the Y tiles IT wrote (hot in own XCD L2),
// transposes via LDS, applies affine+relu, stores coalesced fp32.
__global__ __launch_bounds__(256) void k2f(
    const u32* __restrict__ Gt, const int* __restrict__ ring,
    const float* __restrict__ bias, u32* __restrict__ Y,
    float* __restrict__ gsum, const float* __restrict__ gamma,
    const float* __restrict__ beta, float* __restrict__ out) {
  const int t = threadIdx.x;
  const int gid = t >> 3;    // face within 32-face tile
  const int cs = t & 7;      // 16 B channel slice (channels cs*8 .. cs*8+7)
  const int ntiles = (Fn + 31) / 32;   // 1563

  __shared__ union SM {
    struct { float rs[32][68]; float rs2[32][68]; } s;  // 17408 B
    u32 ys[32][34];                                     // 4352 B
  } sm;

  f32x2 bv2[4];
  #pragma unroll
  for (int p = 0; p < 4; p++) {
    bv2[p].x = bias[cs * 8 + 2 * p];
    bv2[p].y = bias[cs * 8 + 2 * p + 1];
  }

  f32x2 sacc2[4], s2acc2[4];
  #pragma unroll
  for (int p = 0; p < 4; p++) { sacc2[p] = (f32x2)(0.f); s2acc2[p] = (f32x2)(0.f); }

  for (int vs = blockIdx.x; vs < NSUB; vs += gridDim.x) {
    const int b = (vs & 7) >> 1;                    // XCD-pinned: 2 XCDs per b
    const int sub = ((vs >> 3) << 1) | (vs & 1);    // 0..511 within b
    const u32* Gb = Gt + (size_t)b * Fn * 32;
    const int* rb = ring + (size_t)b * Fn * Kn;

    int tile = sub;
    i32x4 r0, r1, r2, r3;
    if (tile < ntiles) {
      int fa = tile * 32 + gid;
      int fc = fa < Fn ? fa : Fn - 1;
      const i32x4* rp = (const i32x4*)(rb + (size_t)fc * Kn);
      r0 = __builtin_nontemporal_load(&rp[0]);
      r1 = __builtin_nontemporal_load(&rp[1]);
      r2 = __builtin_nontemporal_load(&rp[2]);
      r3 = __builtin_nontemporal_load(&rp[3]);
    }

    for (; tile < ntiles; tile += 512) {
      const int fa = tile * 32 + gid;
      const bool valid = fa < Fn;
      int idx[16] = {r0[0],r0[1],r0[2],r0[3], r1[0],r1[1],r1[2],r1[3],
                     r2[0],r2[1],r2[2],r2[3], r3[0],r3[1],r3[2],r3[3]};

      // prefetch next tile's ring indices
      const int ntile = tile + 512;
      if (ntile < ntiles) {
        int nfa = ntile * 32 + gid;
        int nfc = nfa < Fn ? nfa : Fn - 1;
        const i32x4* rp = (const i32x4*)(rb + (size_t)nfc * Kn);
        r0 = __builtin_nontemporal_load(&rp[0]);
        r1 = __builtin_nontemporal_load(&rp[1]);
        r2 = __builtin_nontemporal_load(&rp[2]);
        r3 = __builtin_nontemporal_load(&rp[3]);
      }

      f32x2 acc2[4];
      #pragma unroll
      for (int p = 0; p < 4; p++) acc2[p] = bv2[p];

      u32x4 v[8];
      #pragma unroll
      for (int k = 0; k < 8; k++)
        v[k] = *(const u32x4*)(Gb + (size_t)idx[k] * 32 + cs * 4);
      #pragma unroll
      for (int k = 0; k < 8; k++) {
        #pragma unroll
        for (int p = 0; p < 4; p++) acc2[p] += up2(v[k][p]);  // v_pk_add_f32
      }
      #pragma unroll
      for (int k = 0; k < 8; k++)
        v[k] = *(const u32x4*)(Gb + (size_t)idx[8 + k] * 32 + cs * 4);
      #pragma unroll
      for (int k = 0; k < 8; k++) {
        #pragma unroll
        for (int p = 0; p < 4; p++) acc2[p] += up2(v[k][p]);
      }

      if (valid) {
        u32x4 pv;
        pv[0] = pack2(acc2[0].x, acc2[0].y); pv[1] = pack2(acc2[1].x, acc2[1].y);
        pv[2] = pack2(acc2[2].x, acc2[2].y); pv[3] = pack2(acc2[3].x, acc2[3].y);
        *(u32x4*)(Y + ((size_t)b * Fn + fa) * 32 + cs * 4) = pv;  // cached: re-read in phase 3
        #pragma unroll
        for (int p = 0; p < 4; p++) {
          sacc2[p] += acc2[p];
          s2acc2[p] += acc2[p] * acc2[p];   // v_pk_fma_f32
        }
      }
    }
  }

  // block-level stats reduce + one atomic round
  #pragma unroll
  for (int p = 0; p < 4; p++) {
    sm.s.rs[gid][cs * 8 + 2 * p] = sacc2[p].x;
    sm.s.rs[gid][cs * 8 + 2 * p + 1] = sacc2[p].y;
    sm.s.rs2[gid][cs * 8 + 2 * p] = s2acc2[p].x;
    sm.s.rs2[gid][cs * 8 + 2 * p + 1] = s2acc2[p].y;
  }
  __syncthreads();
  if (t < 64) {
    float s = 0.f;
    #pragma unroll
    for (int g = 0; g < 32; g++) s += sm.s.rs[g][t];
    atomicAdd(&gsum[t], s);
  } else if (t < 128) {
    const int ch = t - 64;
    float s2 = 0.f;
    #pragma unroll
    for (int g = 0; g < 32; g++) s2 += sm.s.rs2[g][ch];
    atomicAdd(&gsum[64 + ch], s2);   // gsum2 = gsum+64
  }

  cg::this_grid().sync();

  // phase 2: per-thread BN coefficients for its channel
  const int ch = t >> 2, fg = t & 3;
  const float inv = 1.0f / (float)NTOT;
  const float mean = gsum[ch] * inv;
  const float var = gsum[64 + ch] * inv - mean * mean;   // biased
  const float a_ = gamma[ch] * rsqrtf(var + EPS);
  const float c_ = beta[ch] - mean * a_;
  const int c2 = ch >> 1;
  const bool hi = ch & 1;

  // phase 3: normalize the same tiles this block gathered (Y hot in own L2)
  for (int vs = blockIdx.x; vs < NSUB; vs += gridDim.x) {
    const int b = (vs & 7) >> 1;
    const int sub = ((vs >> 3) << 1) | (vs & 1);
    const u32* Yb = Y + (size_t)b * Fn * 32;
    for (int tile = sub; tile < ntiles; tile += 512) {
      __syncthreads();             // ys reuse guard
      {
        const int fl = t >> 3, sl = (t & 7) * 4;
        int fa = tile * 32 + fl;
        u32x4 vv = (u32x4)(0u);
        if (fa < Fn) vv = *(const u32x4*)(Yb + (size_t)fa * 32 + sl);
        sm.ys[sl + 0][fl] = vv[0]; sm.ys[sl + 1][fl] = vv[1];
        sm.ys[sl + 2][fl] = vv[2]; sm.ys[sl + 3][fl] = vv[3];
      }
      __syncthreads();
      const int fbase = tile * 32 + fg * 8;
      if (fbase < Fn) {            // Fn%8==0 -> all 8 faces valid together
        float r[8];
        #pragma unroll
        for (int j = 0; j < 8; j++) {
          u32 u = sm.ys[c2][fg * 8 + j];
          float xv = __uint_as_float(hi ? (u & 0xffff0000u) : (u << 16));
          r[j] = fmaxf(fmaf(xv, a_, c_), 0.f);
        }
        float* ob = out + ((size_t)b * 64 + ch) * Fn + fbase;
        *(float4*)ob = make_float4(r[0], r[1], r[2], r[3]);
        *(float4*)(ob + 4) = make_float4(r[4], r[5], r[6], r[7]);
      }
    }
  }
}

// ---------- fallback (non-cooperative) path: proven round-2 kernels ----------
template<int WRITE_BF16>
__global__ __launch_bounds__(256) void k2_gather(
    const u32* __restrict__ Gt, const int* __restrict__ ring,
    const float* __restrict__ bias, u32* __restrict__ Y, float* __restrict__ outF,
    float* __restrict__ gsum, float* __restrict__ gsum2) {
  const int bid = blockIdx.x;
  const int b = (bid & 7) >> 1;
  const int sub = ((bid >> 3) << 1) | (bid & 1);
  const int t = threadIdx.x;
  const int gid = t >> 3;
  const int cs = t & 7;

  __shared__ float rs[32][68];
  __shared__ float rs2[32][68];

  float bv[8];
  #pragma unroll
  for (int i = 0; i < 8; i++) bv[i] = bias[cs * 8 + i];

  const u32* Gb = Gt + (size_t)b * Fn * 32;
  const int* rb = ring + (size_t)b * Fn * Kn;

  float sacc[8], s2acc[8];
  #pragma unroll
  for (int i = 0; i < 8; i++) { sacc[i] = 0.f; s2acc[i] = 0.f; }

  const int ntiles = (Fn + 31) / 32;

  int tile = sub;
  i32x4 r0, r1, r2, r3;
  if (tile < ntiles) {
    int fa = tile * 32 + gid;
    int fc = fa < Fn ? fa : Fn - 1;
    const i32x4* rp = (const i32x4*)(rb + (size_t)fc * Kn);
    r0 = __builtin_nontemporal_load(&rp[0]);
    r1 = __builtin_nontemporal_load(&rp[1]);
    r2 = __builtin_nontemporal_load(&rp[2]);
    r3 = __builtin_nontemporal_load(&rp[3]);
  }

  for (; tile < ntiles; tile += 512) {
    const int fa = tile * 32 + gid;
    const bool valid = fa < Fn;
    int idx[16] = {r0[0],r0[1],r0[2],r0[3], r1[0],r1[1],r1[2],r1[3],
                   r2[0],r2[1],r2[2],r2[3], r3[0],r3[1],r3[2],r3[3]};

    const int ntile = tile + 512;
    if (ntile < ntiles) {
      int nfa = ntile * 32 + gid;
      int nfc = nfa < Fn ? nfa : Fn - 1;
      const i32x4* rp = (const i32x4*)(rb + (size_t)nfc * Kn);
      r0 = __builtin_nontemporal_load(&rp[0]);
      r1 = __builtin_nontemporal_load(&rp[1]);
      r2 = __builtin_nontemporal_load(&rp[2]);
      r3 = __builtin_nontemporal_load(&rp[3]);
    }

    float acc[8];
    #pragma unroll
    for (int i = 0; i < 8; i++) acc[i] = 0.f;

    u32x4 v[8];
    #pragma unroll
    for (int k = 0; k < 8; k++)
      v[k] = *(const u32x4*)(Gb + (size_t)idx[k] * 32 + cs * 4);
    #pragma unroll
    for (int k = 0; k < 8; k++) {
      #pragma unroll
      for (int p = 0; p < 4; p++) {
        u32 uu = v[k][p];
        acc[2*p]   += __uint_as_float(uu << 16);
        acc[2*p+1] += __uint_as_float(uu & 0xffff0000u);
      }
    }
    #pragma unroll
    for (int k = 0; k < 8; k++)
      v[k] = *(const u32x4*)(Gb + (size_t)idx[8 + k] * 32 + cs * 4);
    #pragma unroll
    for (int k = 0; k < 8; k++) {
      #pragma unroll
      for (int p = 0; p < 4; p++) {
        u32 uu = v[k][p];
        acc[2*p]   += __uint_as_float(uu << 16);
        acc[2*p+1] += __uint_as_float(uu & 0xffff0000u);
      }
    }

    float yv[8];
    #pragma unroll
    for (int i = 0; i < 8; i++) yv[i] = acc[i] + bv[i];

    if (valid) {
      if (WRITE_BF16) {
        u32x4 pv;
        pv[0] = pack2(yv[0], yv[1]); pv[1] = pack2(yv[2], yv[3]);
        pv[2] = pack2(yv[4], yv[5]); pv[3] = pack2(yv[6], yv[7]);
        __builtin_nontemporal_store(pv,
            (u32x4*)(Y + ((size_t)b * Fn + fa) * 32 + cs * 4));
      } else {
        #pragma unroll
        for (int i = 0; i < 8; i++)
          outF[((size_t)b * 64 + cs * 8 + i) * Fn + fa] = yv[i];
      }
      #pragma unroll
      for (int i = 0; i < 8; i++) {
        sacc[i] += yv[i];
        s2acc[i] += yv[i] * yv[i];
      }
    }
  }

  #pragma unroll
  for (int i = 0; i < 8; i++) {
    rs[gid][cs * 8 + i] = sacc[i];
    rs2[gid][cs * 8 + i] = s2acc[i];
  }
  __syncthreads();
  if (t < 64) {
    float s = 0.f;
    #pragma unroll
    for (int g = 0; g < 32; g++) s += rs[g][t];
    atomicAdd(&gsum[t], s);
  } else if (t < 128) {
    const int ch = t - 64;
    float s2 = 0.f;
    #pragma unroll
    for (int g = 0; g < 32; g++) s2 += rs2[g][ch];
    atomicAdd(&gsum2[ch], s2);
  }
}

__global__ void k3_stats(const float* __restrict__ gsum, const float* __restrict__ gsum2,
                         const float* __restrict__ gamma, const float* __restrict__ beta,
                         float* __restrict__ ab) {
  int o = threadIdx.x;
  if (o < 64) {
    float inv = 1.0f / (float)NTOT;
    float mean = gsum[o] * inv;
    float var = gsum2[o] * inv - mean * mean;
    float r = rsqrtf(var + EPS);
    float a = gamma[o] * r;
    ab[o] = a;
    ab[64 + o] = beta[o] - mean * a;
  }
}

__global__ __launch_bounds__(256) void k4_norm_bf(
    const u32* __restrict__ Y, const float* __restrict__ gsum,
    const float* __restrict__ gsum2, const float* __restrict__ gamma,
    const float* __restrict__ beta, float* __restrict__ out) {
  const int b = blockIdx.y;
  const int f0 = blockIdx.x * 64;
  const int t = threadIdx.x;
  __shared__ u32 ys[32][65];

  #pragma unroll
  for (int j = 0; j < 2; j++) {
    int o = j * 1024 + t * 4;
    int fl = o >> 5, sl = o & 31;
    u32x4 vv = (u32x4)(0u);
    if (f0 + fl < Fn)
      vv = *(const u32x4*)(Y + ((size_t)b * Fn + f0 + fl) * 32 + sl);
    ys[sl + 0][fl] = vv[0]; ys[sl + 1][fl] = vv[1];
    ys[sl + 2][fl] = vv[2]; ys[sl + 3][fl] = vv[3];
  }
  __syncthreads();

  const float inv = 1.0f / (float)NTOT;
  const int fi = t & 15, g = t >> 4;
  const int fbase = 4 * fi;
  #pragma unroll
  for (int j = 0; j < 4; j++) {
    int ch = g * 4 + j;
    float mean = gsum[ch] * inv;
    float var = gsum2[ch] * inv - mean * mean;
    float a = gamma[ch] * rsqrtf(var + EPS);
    float cc = beta[ch] - mean * a;
    if (f0 + fbase < Fn) {
      const int c2 = ch >> 1;
      const bool hi = ch & 1;
      float r[4];
      #pragma unroll
      for (int rr = 0; rr < 4; rr++) {
        u32 u = ys[c2][fbase + rr];
        float xv = __uint_as_float(hi ? (u & 0xffff0000u) : (u << 16));
        r[rr] = fmaxf(fmaf(xv, a, cc), 0.f);
      }
      float4 res = make_float4(r[0], r[1], r[2], r[3]);
      *(float4*)(out + ((size_t)b * 64 + ch) * Fn + f0 + fbase) = res;
    }
  }
}

__global__ __launch_bounds__(256) void k4_norm_f32(float* __restrict__ out,
                                                   const float* __restrict__ ab) {
  int i = blockIdx.x * 256 + threadIdx.x;
  int o = (i / (Fn / 4)) & 63;
  float a = ab[o], c = ab[64 + o];
  float4 v = ((float4*)out)[i];
  v.x = fmaxf(fmaf(v.x, a, c), 0.f);
  v.y = fmaxf(fmaf(v.y, a, c), 0.f);
  v.z = fmaxf(fmaf(v.z, a, c), 0.f);
  v.w = fmaxf(fmaf(v.w, a, c), 0.f);
  ((float4*)out)[i] = v;
}

extern "C" void kernel_launch(void* const* d_in, const int* in_sizes, int n_in,
                              void* d_out, int out_size, void* d_ws, size_t ws_size,
                              hipStream_t stream) {
  const float* fea   = (const float*)d_in[0];
  const int*   ring  = (const int*)d_in[1];
  const float* W     = (const float*)d_in[2];
  const float* bias  = (const float*)d_in[3];
  const float* gamma = (const float*)d_in[4];
  const float* beta  = (const float*)d_in[5];
  float* out = (float*)d_out;

  u32* Gt = (u32*)d_ws;                                   // [B][Fn][32 u32] = 25.6 MB
  const size_t gtBytes = (size_t)Bn * Fn * 32 * 4;
  const size_t yBytes  = (size_t)Bn * Fn * 32 * 4;        // 25.6 MB
  const bool bf16y = ws_size >= gtBytes + yBytes + 1024;

  u32* Y = Gt + (size_t)Bn * Fn * 32;
  float* gsum  = bf16y ? (float*)((char*)d_ws + gtBytes + yBytes)
                       : (float*)((char*)d_ws + gtBytes);
  float* gsum2 = gsum + 64;
  float* ab    = gsum + 128;

  // dispatch 1: GEMM (also zeroes gsum[0..127])
  k1_mfma<<<dim3((Fn + 127) / 128, Bn), 256, 0, stream>>>(fea, W, Gt, gsum);

  bool done = false;
  if (bf16y) {
    // dispatch 2: fused cooperative gather+stats+normalize
    int nb = 0;
    hipError_t oe = hipOccupancyMaxActiveBlocksPerMultiprocessor(&nb, k2f, 256, 0);
    if (oe == hipSuccess && nb > 0) {
      int G = nb * 256;                      // 256 CUs on MI355X
      if (G > NSUB) G = NSUB;
      void* args[] = {(void*)&Gt, (void*)&ring, (void*)&bias, (void*)&Y,
                      (void*)&gsum, (void*)&gamma, (void*)&beta, (void*)&out};
      hipError_t le = hipLaunchCooperativeKernel((const void*)k2f, dim3(G),
                                                 dim3(256), args, 0, stream);
      done = (le == hipSuccess);
    }
    if (!done) {   // fallback: proven 3-dispatch path
      k2_gather<1><<<dim3(NSUB), 256, 0, stream>>>(Gt, ring, bias, Y, out, gsum, gsum2);
      k4_norm_bf<<<dim3((Fn + 63) / 64, Bn), 256, 0, stream>>>(Y, gsum, gsum2, gamma, beta, out);
    }
  } else {
    k2_gather<0><<<dim3(NSUB), 256, 0, stream>>>(Gt, ring, bias, Y, out, gsum, gsum2);
    k3_stats<<<1, 64, 0, stream>>>(gsum, gsum2, gamma, beta, ab);
    k4_norm_f32<<<dim3((Bn * Cn * Fn / 4) / 256), 256, 0, stream>>>(out, ab);
  }
}